// Round 15
// baseline (14567.659 us; speedup 1.0000x reference)
//
#include <hip/hip_runtime.h>
#include <hip/hip_bf16.h>

typedef __hip_bfloat16 bf16;
typedef __attribute__((ext_vector_type(8))) short short8;
typedef __attribute__((ext_vector_type(8))) _Float16 half8;
typedef __attribute__((ext_vector_type(4))) float f32x4;
typedef __attribute__((ext_vector_type(4))) int   int4v;

#define Bb   64
#define Tt   12
#define Nn   1024
#define HORt 12
#define Hh   128
#define Ee   16
#define Mm   20
#define MDd  64
#define DECHd 192
#define CPe  160               // padded enc cat width (129 -> 160)
#define JPe  (Bb*CPe)          // 10240
#define CPd  224               // padded dec cat width (194 -> 224)
#define JPd  (Bb*CPd)          // 14336
#define LDZR 384               // decoder zr stride (bf16)
#define ZRE  256               // encoder zr stride (fp32)

#define INV_SCALE (1.f/4096.f)

// LDS chunk swizzle (2-way-max; XOR involution, r12-verified bit-identical)
#define SWZ(row) (((row) >> 1) & 3)

// async global->LDS: wave-uniform LDS base + lane*16; per-lane global src.
#define GLOAD_LDS16(gp, lp) \
    __builtin_amdgcn_global_load_lds((const __attribute__((address_space(1))) void*)(gp), \
                                     (__attribute__((address_space(3))) void*)(lp), 16, 0, 0)

__device__ __forceinline__ float b2f(bf16 v){ return __bfloat162float(v); }
__device__ __forceinline__ bf16  f2b(float v){ return __float2bfloat16(v); }
__device__ __forceinline__ void splitf16(float v, ushort& hi, ushort& lo){
    _Float16 h = (_Float16)v;
    _Float16 l = (_Float16)(v - (float)h);
    hi = __builtin_bit_cast(ushort, h);
    lo = __builtin_bit_cast(ushort, l);
}

// ---------------------------------------------------------------------------
__global__ void ws_probe_kernel(float* __restrict__ out, float val)
{
    size_t i = (size_t)blockIdx.x*256 + threadIdx.x;
    out[i] = val;
}

__global__ void conv_f2b(const float* __restrict__ src, bf16* __restrict__ dst)
{
    size_t i = (size_t)blockIdx.x*256 + threadIdx.x;
    dst[i] = f2b(src[i]);
}

__global__ void conv_split(const float* __restrict__ src, ushort* __restrict__ hi,
                           ushort* __restrict__ lo, float scale)
{
    size_t i = (size_t)blockIdx.x*256 + threadIdx.x;
    splitf16(src[i]*scale, hi[i], lo[i]);
}

// encoder weights TRANSPOSED: fp32 (3*C x No) -> f16 hi/lo [3][No][CP] x256
__global__ void conv_w_split_T(const float* __restrict__ W, ushort* __restrict__ hi,
                               ushort* __restrict__ lo, int C, int CP, int No)
{
    int idx = blockIdx.x*256 + threadIdx.x;
    if (idx >= 3*No*CP) return;
    int km = idx / (No*CP);
    int r  = idx % (No*CP);
    int o  = r / CP, k = r % CP;
    float v = (k < C) ? W[(size_t)(km*C + k)*No + o]*256.f : 0.f;
    splitf16(v, hi[idx], lo[idx]);
}

// decoder weights TRANSPOSED: fp32 (3*C x No) -> bf16 [3][NoP][CP]
__global__ void conv_w_T(const float* __restrict__ W, bf16* __restrict__ dst,
                         int C, int CP, int No, int NoP)
{
    int idx = blockIdx.x*256 + threadIdx.x;
    if (idx >= 3*NoP*CP) return;
    int km = idx / (NoP*CP);
    int r  = idx % (NoP*CP);
    int o  = r / CP, k = r % CP;
    dst[idx] = (k < C && o < No) ? f2b(W[(size_t)(km*C + k)*No + o]) : f2b(0.f);
}

// ---------------------------------------------------------------------------
// supports = softmax(relu(emb @ emb^T), axis=1)  (fp32, verified)
// ---------------------------------------------------------------------------
__global__ __launch_bounds__(256) void supports_kernel(const float* __restrict__ emb,
                                                       float* __restrict__ S)
{
    int n = blockIdx.x;
    __shared__ float row[Nn];
    __shared__ float en[Ee];
    __shared__ float red[256];
    int tid = threadIdx.x;
    if (tid < Ee) en[tid] = emb[n*Ee + tid];
    __syncthreads();
    float lmax = -1e30f;
    for (int j = tid; j < Nn; j += 256){
        float d = 0.f;
        #pragma unroll
        for (int e = 0; e < Ee; ++e) d += en[e]*emb[j*Ee + e];
        d = d > 0.f ? d : 0.f;
        row[j] = d;
        lmax = fmaxf(lmax, d);
    }
    red[tid] = lmax; __syncthreads();
    for (int s = 128; s > 0; s >>= 1){ if (tid < s) red[tid] = fmaxf(red[tid], red[tid+s]); __syncthreads(); }
    float mx = red[0]; __syncthreads();
    float lsum = 0.f;
    for (int j = tid; j < Nn; j += 256){ float e = expf(row[j]-mx); row[j] = e; lsum += e; }
    red[tid] = lsum; __syncthreads();
    for (int s = 128; s > 0; s >>= 1){ if (tid < s) red[tid] += red[tid+s]; __syncthreads(); }
    float inv = 1.f/red[0];
    for (int j = tid; j < Nn; j += 256) S[n*Nn + j] = row[j]*inv;
}

// ---------------------------------------------------------------------------
// T2 = 2*S@S - I   (fp32, verified)
// ---------------------------------------------------------------------------
__global__ __launch_bounds__(256) void t2_gemm(const float* __restrict__ S,
                                               float* __restrict__ T2)
{
    int n0 = blockIdx.y*64, j0 = blockIdx.x*64;
    __shared__ float As[16][65];
    __shared__ float Xs[16][65];
    int tid = threadIdx.x; int tx = tid & 15, ty = tid >> 4;
    float acc[4][4] = {};
    for (int k0 = 0; k0 < Nn; k0 += 16){
        #pragma unroll
        for (int r = 0; r < 4; ++r){
            int idx = tid + r*256;
            int ar = idx >> 4, ak = idx & 15;
            As[ak][ar] = S[(n0+ar)*Nn + k0+ak];
        }
        #pragma unroll
        for (int r = 0; r < 4; ++r){
            int idx = tid + r*256;
            int xm = idx >> 6, xj = idx & 63;
            Xs[xm][xj] = S[(k0+xm)*Nn + j0+xj];
        }
        __syncthreads();
        #pragma unroll
        for (int kk = 0; kk < 16; ++kk){
            float a[4], xv[4];
            #pragma unroll
            for (int i = 0; i < 4; ++i) a[i]  = As[kk][ty*4+i];
            #pragma unroll
            for (int j = 0; j < 4; ++j) xv[j] = Xs[kk][tx*4+j];
            #pragma unroll
            for (int i = 0; i < 4; ++i)
                #pragma unroll
                for (int j = 0; j < 4; ++j) acc[i][j] += a[i]*xv[j];
        }
        __syncthreads();
    }
    #pragma unroll
    for (int i = 0; i < 4; ++i){
        int n = n0 + ty*4 + i;
        #pragma unroll
        for (int j = 0; j < 4; ++j){
            int c = j0 + tx*4 + j;
            T2[n*Nn + c] = 2.f*acc[i][j] - (n == c ? 1.f : 0.f);
        }
    }
}

// ---------------------------------------------------------------------------
// FUSED encoder cat builder + transpose (r14-verified)
// ---------------------------------------------------------------------------
template<int PHASE>
__global__ __launch_bounds__(256) void build_encT(
    const float* __restrict__ x, const float* __restrict__ h,
    const float* __restrict__ zre,
    ushort* __restrict__ chi, ushort* __restrict__ clo,
    ushort* __restrict__ cThi, ushort* __restrict__ cTlo, int t)
{
    __shared__ ushort th[64][66];
    __shared__ ushort tl[64][66];
    int j0 = blockIdx.x*64, n0 = blockIdx.y*64;
    for (int i = threadIdx.x; i < 4096; i += 256){
        int r = i >> 6, cc = i & 63;
        int n = n0 + r, j = j0 + cc;
        int b = j / CPe, c = j % CPe;
        size_t rb = (size_t)n*64 + b;
        float v;
        if (c == 0)       v = x[((size_t)b*Tt + t)*Nn + n];
        else if (c < 129) v = (PHASE == 1) ? h[rb*Hh + (c-1)]
                                           : zre[rb*ZRE + (c-1)] * h[rb*Hh + (c-1)];
        else              v = 0.f;
        ushort hi, lo; splitf16(v*16.f, hi, lo);
        th[r][cc] = hi; tl[r][cc] = lo;
        chi[(size_t)n*JPe + j] = hi;
        clo[(size_t)n*JPe + j] = lo;
    }
    __syncthreads();
    for (int i = threadIdx.x; i < 4096; i += 256){
        int cc = i >> 6, r = i & 63;
        size_t d = (size_t)(j0+cc)*1024 + n0 + r;
        cThi[d] = th[r][cc];
        cTlo[d] = tl[r][cc];
    }
}

// ---------------------------------------------------------------------------
// FUSED decoder cat builder + transpose (r14-verified)
// ---------------------------------------------------------------------------
template<int PHASE>
__global__ __launch_bounds__(256) void build_decT(
    const float* __restrict__ go, const float* __restrict__ yc,
    const float* __restrict__ h, const bf16* __restrict__ zrb,
    bf16* __restrict__ cat, bf16* __restrict__ catT, int t)
{
    __shared__ ushort tt[64][66];
    int j0 = blockIdx.x*64, n0 = blockIdx.y*64;
    for (int i = threadIdx.x; i < 4096; i += 256){
        int r = i >> 6, cc = i & 63;
        int n = n0 + r, j = j0 + cc;
        int b = j / CPd, c = j % CPd;
        size_t rb = (size_t)n*64 + b;
        float v;
        if (c == 0)       v = go[rb];
        else if (c == 1)  v = yc[((size_t)b*HORt + t)*Nn + n];
        else if (c < 194) v = (PHASE == 1) ? h[rb*DECHd + (c-2)]
                                           : b2f(zrb[rb*LDZR + (c-2)]) * h[rb*DECHd + (c-2)];
        else              v = 0.f;
        bf16 bv = f2b(v);
        tt[r][cc] = __builtin_bit_cast(ushort, bv);
        cat[(size_t)n*JPd + j] = bv;
    }
    __syncthreads();
    for (int i = threadIdx.x; i < 4096; i += 256){
        int cc = i >> 6, r = i & 63;
        bf16 bv = __builtin_bit_cast(bf16, tt[r][cc]);
        catT[(size_t)(j0+cc)*1024 + n0 + r] = bv;
    }
}

// ---------------------------------------------------------------------------
// GCN split-fp16 3-pass MFMA, BM=256 x BN=128 (halves B re-reads vs BM=128).
// Per-wave 64x128 output; per-output K/MFMA order identical to the 128^2
// kernel -> bit-identical results.
// ---------------------------------------------------------------------------
__global__ __launch_bounds__(256) void mfma_split_gcn(
    const ushort* __restrict__ Ah, const ushort* __restrict__ Al,
    const ushort* __restrict__ BhT, const ushort* __restrict__ BlT,
    int Ksz, int lda, int ldbT,
    ushort* __restrict__ OutHi, ushort* __restrict__ OutLo, int ldc)
{
    __shared__ short Ah_s[256*32];
    __shared__ short Al_s[256*32];
    __shared__ short Bh_s[128*32];
    __shared__ short Bl_s[128*32];
    int tid = threadIdx.x;
    int m0 = blockIdx.y * 256;
    int n0 = blockIdx.x * 128;
    int wave = tid >> 6, lane = tid & 63;
    int lr = lane & 15, lk8 = lane >> 4;
    int wbase = wave * 1024;

    f32x4 acc[4][8];
    #pragma unroll
    for (int i = 0; i < 4; ++i)
        #pragma unroll
        for (int j = 0; j < 8; ++j) acc[i][j] = (f32x4){0.f,0.f,0.f,0.f};

    for (int k0 = 0; k0 < Ksz; k0 += 32){
        #pragma unroll
        for (int r = 0; r < 4; ++r){
            int i = tid + r*256;
            int row = i >> 2, q = i & 3;
            int sq = q ^ SWZ(row);
            size_t soA = (size_t)(m0+row)*lda + k0 + sq*8;
            int lofs = r*4096 + wbase;
            GLOAD_LDS16(Ah + soA, (char*)Ah_s + lofs);
            GLOAD_LDS16(Al + soA, (char*)Al_s + lofs);
        }
        #pragma unroll
        for (int r = 0; r < 2; ++r){
            int i = tid + r*256;
            int row = i >> 2, q = i & 3;
            int sq = q ^ SWZ(row);
            size_t soB = (size_t)(n0+row)*ldbT + k0 + sq*8;
            int lofs = r*4096 + wbase;
            GLOAD_LDS16(BhT + soB, (char*)Bh_s + lofs);
            GLOAD_LDS16(BlT + soB, (char*)Bl_s + lofs);
        }
        __syncthreads();
        half8 ah[4], al[4], bh[8], bl[8];
        #pragma unroll
        for (int mi = 0; mi < 4; ++mi){
            int row = wave*64 + mi*16 + lr;
            int off = row*64 + ((lk8 ^ SWZ(row)) << 4);
            ah[mi] = *(const half8*)((const char*)Ah_s + off);
            al[mi] = *(const half8*)((const char*)Al_s + off);
        }
        #pragma unroll
        for (int ni = 0; ni < 8; ++ni){
            int col = ni*16 + lr;
            int off = col*64 + ((lk8 ^ SWZ(col)) << 4);
            bh[ni] = *(const half8*)((const char*)Bh_s + off);
            bl[ni] = *(const half8*)((const char*)Bl_s + off);
        }
        #pragma unroll
        for (int mi = 0; mi < 4; ++mi)
            #pragma unroll
            for (int ni = 0; ni < 8; ++ni){
                acc[mi][ni] = __builtin_amdgcn_mfma_f32_16x16x32_f16(ah[mi], bh[ni], acc[mi][ni], 0, 0, 0);
                acc[mi][ni] = __builtin_amdgcn_mfma_f32_16x16x32_f16(ah[mi], bl[ni], acc[mi][ni], 0, 0, 0);
                acc[mi][ni] = __builtin_amdgcn_mfma_f32_16x16x32_f16(al[mi], bh[ni], acc[mi][ni], 0, 0, 0);
            }
        __syncthreads();
    }

    int rbase = lk8 * 4;
    #pragma unroll
    for (int mi = 0; mi < 4; ++mi){
        #pragma unroll
        for (int ni = 0; ni < 8; ++ni){
            int gn = n0 + ni*16 + lr;
            #pragma unroll
            for (int rg = 0; rg < 4; ++rg){
                int gm = m0 + wave*64 + mi*16 + rbase + rg;
                float v = acc[mi][ni][rg] * INV_SCALE;
                ushort h, l;
                splitf16(v, h, l);
                OutHi[(size_t)gm*ldc + gn] = h;
                OutLo[(size_t)gm*ldc + gn] = l;
            }
        }
    }
}

// ---------------------------------------------------------------------------
// GCN decoder bf16 MFMA, BM=256 x BN=128 (bit-identical math to 128^2)
// ---------------------------------------------------------------------------
__global__ __launch_bounds__(256) void mfma_gemm_gcn(
    const ushort* __restrict__ A, const ushort* __restrict__ BT,
    int Ksz, int lda, int ldbT,
    bf16* __restrict__ Cout, int ldc)
{
    __shared__ short As[256*32];
    __shared__ short Bs[128*32];
    int tid = threadIdx.x;
    int m0 = blockIdx.y * 256;
    int n0 = blockIdx.x * 128;
    int wave = tid >> 6, lane = tid & 63;
    int lr = lane & 15, lk8 = lane >> 4;
    int wbase = wave * 1024;

    f32x4 acc[4][8];
    #pragma unroll
    for (int i = 0; i < 4; ++i)
        #pragma unroll
        for (int j = 0; j < 8; ++j) acc[i][j] = (f32x4){0.f,0.f,0.f,0.f};

    for (int k0 = 0; k0 < Ksz; k0 += 32){
        #pragma unroll
        for (int r = 0; r < 4; ++r){
            int i = tid + r*256;
            int row = i >> 2, q = i & 3;
            int sq = q ^ SWZ(row);
            size_t soA = (size_t)(m0+row)*lda + k0 + sq*8;
            GLOAD_LDS16(A + soA, (char*)As + r*4096 + wbase);
        }
        #pragma unroll
        for (int r = 0; r < 2; ++r){
            int i = tid + r*256;
            int row = i >> 2, q = i & 3;
            int sq = q ^ SWZ(row);
            size_t soB = (size_t)(n0+row)*ldbT + k0 + sq*8;
            GLOAD_LDS16(BT + soB, (char*)Bs + r*4096 + wbase);
        }
        __syncthreads();
        short8 af[4], bfv[8];
        #pragma unroll
        for (int mi = 0; mi < 4; ++mi){
            int row = wave*64 + mi*16 + lr;
            int off = row*64 + ((lk8 ^ SWZ(row)) << 4);
            af[mi] = *(const short8*)((const char*)As + off);
        }
        #pragma unroll
        for (int ni = 0; ni < 8; ++ni){
            int col = ni*16 + lr;
            int off = col*64 + ((lk8 ^ SWZ(col)) << 4);
            bfv[ni] = *(const short8*)((const char*)Bs + off);
        }
        #pragma unroll
        for (int mi = 0; mi < 4; ++mi)
            #pragma unroll
            for (int ni = 0; ni < 8; ++ni)
                acc[mi][ni] = __builtin_amdgcn_mfma_f32_16x16x32_bf16(
                                  af[mi], bfv[ni], acc[mi][ni], 0, 0, 0);
        __syncthreads();
    }

    int rbase = lk8 * 4;
    #pragma unroll
    for (int mi = 0; mi < 4; ++mi){
        #pragma unroll
        for (int ni = 0; ni < 8; ++ni){
            int gn = n0 + ni*16 + lr;
            #pragma unroll
            for (int rg = 0; rg < 4; ++rg){
                int gm = m0 + wave*64 + mi*16 + rbase + rg;
                Cout[(size_t)gm*ldc + gn] = f2b(acc[mi][ni][rg]);
            }
        }
    }
}

// ---------------------------------------------------------------------------
// split-fp16 3-pass MFMA GEMM, 128^2 (r14-verified; gate/update only)
// ---------------------------------------------------------------------------
template<int EPI>
__global__ __launch_bounds__(256) void mfma_split(
    const ushort* __restrict__ Ah0, const ushort* __restrict__ Al0,
    const ushort* __restrict__ Ah1, const ushort* __restrict__ Al1,
    const ushort* __restrict__ Ah2, const ushort* __restrict__ Al2,
    const ushort* __restrict__ BhT0, const ushort* __restrict__ BlT0,
    const ushort* __restrict__ BhT1, const ushort* __restrict__ BlT1,
    const ushort* __restrict__ BhT2, const ushort* __restrict__ BlT2,
    int nmat, int Ksz, int lda, int ldbT,
    ushort* __restrict__ OutHi, ushort* __restrict__ OutLo, int ldc, int Ncols,
    float* __restrict__ OutF, int ldo,
    const float* __restrict__ bias, const float* __restrict__ zrf,
    float* __restrict__ hbuf, int Hd)
{
    __shared__ short Ah_s[128*32];
    __shared__ short Al_s[128*32];
    __shared__ short Bh_s[128*32];
    __shared__ short Bl_s[128*32];
    int tid = threadIdx.x;
    int m0 = blockIdx.y * 128;
    int n0 = blockIdx.x * 128;
    int wave = tid >> 6, lane = tid & 63;
    int wr = wave >> 1, wc = wave & 1;
    int lr = lane & 15, lk8 = lane >> 4;

    f32x4 acc[4][4];
    #pragma unroll
    for (int i = 0; i < 4; ++i)
        #pragma unroll
        for (int j = 0; j < 4; ++j) acc[i][j] = (f32x4){0.f,0.f,0.f,0.f};

    const ushort* Ahs[3] = {Ah0, Ah1, Ah2};
    const ushort* Als[3] = {Al0, Al1, Al2};
    const ushort* Bhs[3] = {BhT0, BhT1, BhT2};
    const ushort* Bls[3] = {BlT0, BlT1, BlT2};

    int wbase = wave * 1024;

    for (int km = 0; km < nmat; ++km){
        const ushort* Agh = Ahs[km]; const ushort* Agl = Als[km];
        const ushort* Bgh = Bhs[km]; const ushort* Bgl = Bls[km];
        for (int k0 = 0; k0 < Ksz; k0 += 32){
            #pragma unroll
            for (int r = 0; r < 2; ++r){
                int i = tid + r*256;
                int row = i >> 2, q = i & 3;
                int sq = q ^ SWZ(row);
                size_t soA = (size_t)(m0+row)*lda  + k0 + sq*8;
                size_t soB = (size_t)(n0+row)*ldbT + k0 + sq*8;
                int lofs = r*4096 + wbase;
                GLOAD_LDS16(Agh + soA, (char*)Ah_s + lofs);
                GLOAD_LDS16(Agl + soA, (char*)Al_s + lofs);
                GLOAD_LDS16(Bgh + soB, (char*)Bh_s + lofs);
                GLOAD_LDS16(Bgl + soB, (char*)Bl_s + lofs);
            }
            __syncthreads();
            half8 ah[4], al[4], bh[4], bl[4];
            #pragma unroll
            for (int mi = 0; mi < 4; ++mi){
                int row = wr*64 + mi*16 + lr;
                int off = row*64 + ((lk8 ^ SWZ(row)) << 4);
                ah[mi] = *(const half8*)((const char*)Ah_s + off);
                al[mi] = *(const half8*)((const char*)Al_s + off);
            }
            #pragma unroll
            for (int ni = 0; ni < 4; ++ni){
                int col = wc*64 + ni*16 + lr;
                int off = col*64 + ((lk8 ^ SWZ(col)) << 4);
                bh[ni] = *(const half8*)((const char*)Bh_s + off);
                bl[ni] = *(const half8*)((const char*)Bl_s + off);
            }
            #pragma unroll
            for (int mi = 0; mi < 4; ++mi)
                #pragma unroll
                for (int ni = 0; ni < 4; ++ni){
                    acc[mi][ni] = __builtin_amdgcn_mfma_f32_16x16x32_f16(ah[mi], bh[ni], acc[mi][ni], 0, 0, 0);
                    acc[mi][ni] = __builtin_amdgcn_mfma_f32_16x16x32_f16(ah[mi], bl[ni], acc[mi][ni], 0, 0, 0);
                    acc[mi][ni] = __builtin_amdgcn_mfma_f32_16x16x32_f16(al[mi], bh[ni], acc[mi][ni], 0, 0, 0);
                }
            __syncthreads();
        }
    }

    int rbase = lk8 * 4;
    #pragma unroll
    for (int mi = 0; mi < 4; ++mi){
        #pragma unroll
        for (int ni = 0; ni < 4; ++ni){
            int gn = n0 + wc*64 + ni*16 + lr;
            if (gn >= Ncols) continue;
            #pragma unroll
            for (int rg = 0; rg < 4; ++rg){
                int gm = m0 + wr*64 + mi*16 + rbase + rg;
                float v = acc[mi][ni][rg] * INV_SCALE;
                if (EPI == 0){
                    ushort h, l;
                    splitf16(v, h, l);
                    OutHi[(size_t)gm*ldc + gn] = h;
                    OutLo[(size_t)gm*ldc + gn] = l;
                } else if (EPI == 1){
                    v += bias[gn];
                    OutF[(size_t)gm*ldo + gn] = 1.f/(1.f + expf(-v));
                } else {
                    float hc = tanhf(v + bias[gn]);
                    float rr = zrf[(size_t)gm*ldo + Hd + gn];
                    float ho = hbuf[(size_t)gm*Hd + gn];
                    hbuf[(size_t)gm*Hd + gn] = rr*ho + (1.f-rr)*hc;
                }
            }
        }
    }
}

// ---------------------------------------------------------------------------
// decoder bf16 MFMA GEMM, 128^2 (r14-verified; gate/update only)
// ---------------------------------------------------------------------------
template<int EPI>
__global__ __launch_bounds__(256) void mfma_gemm(
    const ushort* __restrict__ A0, const ushort* __restrict__ A1, const ushort* __restrict__ A2,
    const ushort* __restrict__ BT0, const ushort* __restrict__ BT1, const ushort* __restrict__ BT2,
    int nmat, int Ksz, int lda, int ldbT,
    bf16* __restrict__ Cout, int ldc, int Ncols,
    const float* __restrict__ bias,
    const bf16* __restrict__ zr, float* __restrict__ hbuf, int Hd)
{
    __shared__ short As[128*32];
    __shared__ short Bs[128*32];
    int tid = threadIdx.x;
    int m0 = blockIdx.y * 128;
    int n0 = blockIdx.x * 128;
    int wave = tid >> 6, lane = tid & 63;
    int wr = wave >> 1, wc = wave & 1;
    int lr = lane & 15, lk8 = lane >> 4;

    f32x4 acc[4][4];
    #pragma unroll
    for (int i = 0; i < 4; ++i)
        #pragma unroll
        for (int j = 0; j < 4; ++j) acc[i][j] = (f32x4){0.f,0.f,0.f,0.f};

    const ushort* Aps[3] = {A0, A1, A2};
    const ushort* Bps[3] = {BT0, BT1, BT2};

    int wbase = wave * 1024;

    for (int km = 0; km < nmat; ++km){
        const ushort* Ag = Aps[km];
        const ushort* Bg = Bps[km];
        for (int k0 = 0; k0 < Ksz; k0 += 32){
            #pragma unroll
            for (int r = 0; r < 2; ++r){
                int i = tid + r*256;
                int row = i >> 2, q = i & 3;
                int sq = q ^ SWZ(row);
                size_t soA = (size_t)(m0+row)*lda  + k0 + sq*8;
                size_t soB = (size_t)(n0+row)*ldbT + k0 + sq*8;
                int lofs = r*4096 + wbase;
                GLOAD_LDS16(Ag + soA, (char*)As + lofs);
                GLOAD_LDS16(Bg + soB, (char*)Bs + lofs);
            }
            __syncthreads();
            short8 af[4], bfv[4];
            #pragma unroll
            for (int mi = 0; mi < 4; ++mi){
                int row = wr*64 + mi*16 + lr;
                int off = row*64 + ((lk8 ^ SWZ(row)) << 4);
                af[mi] = *(const short8*)((const char*)As + off);
            }
            #pragma unroll
            for (int ni = 0; ni < 4; ++ni){
                int col = wc*64 + ni*16 + lr;
                int off = col*64 + ((lk8 ^ SWZ(col)) << 4);
                bfv[ni] = *(const short8*)((const char*)Bs + off);
            }
            #pragma unroll
            for (int mi = 0; mi < 4; ++mi)
                #pragma unroll
                for (int ni = 0; ni < 4; ++ni)
                    acc[mi][ni] = __builtin_amdgcn_mfma_f32_16x16x32_bf16(
                                      af[mi], bfv[ni], acc[mi][ni], 0, 0, 0);
            __syncthreads();
        }
    }

    int rbase = lk8 * 4;
    #pragma unroll
    for (int mi = 0; mi < 4; ++mi){
        #pragma unroll
        for (int ni = 0; ni < 4; ++ni){
            int gn = n0 + wc*64 + ni*16 + lr;
            if (gn >= Ncols) continue;
            #pragma unroll
            for (int rg = 0; rg < 4; ++rg){
                int gm = m0 + wr*64 + mi*16 + rbase + rg;
                float v = acc[mi][ni][rg];
                if (EPI == 0){
                    Cout[(size_t)gm*ldc + gn] = f2b(v);
                } else if (EPI == 1){
                    v += bias[gn];
                    Cout[(size_t)gm*ldc + gn] = f2b(1.f/(1.f + expf(-v)));
                } else {
                    float hc = tanhf(v + bias[gn]);
                    float rr = b2f(zr[(size_t)gm*LDZR + Hd + gn]);
                    float ho = hbuf[(size_t)gm*Hd + gn];
                    hbuf[(size_t)gm*Hd + gn] = rr*ho + (1.f-rr)*hc;
                }
            }
        }
    }
}

// ---------------------------------------------------------------------------
// attention (fp32, verified)
// ---------------------------------------------------------------------------
__global__ __launch_bounds__(64) void attn_kernel(const float* __restrict__ hT,
                                                  const float* __restrict__ Wq,
                                                  const float* __restrict__ Mem,
                                                  float* __restrict__ hdec,
                                                  int* __restrict__ ind0,
                                                  float* __restrict__ outv,
                                                  float* __restrict__ outq,
                                                  float* __restrict__ outp)
{
    int rb = blockIdx.x; int n = rb / Bb, b = rb % Bb;
    int tid = threadIdx.x;
    __shared__ float hl[Hh];
    __shared__ float ql[MDd];
    __shared__ float sm[Mm];
    __shared__ float stats[2];
    __shared__ int   smind;
    hl[tid]      = hT[(size_t)rb*Hh + tid];
    hl[tid + 64] = hT[(size_t)rb*Hh + tid + 64];
    __syncthreads();
    float q = 0.f;
    for (int hh = 0; hh < Hh; ++hh) q += hl[hh]*Wq[hh*MDd + tid];
    ql[tid] = q;
    size_t bn = (size_t)b*Nn + n;
    outq[bn*MDd + tid] = q;
    __syncthreads();
    if (tid < Mm){
        float s = 0.f;
        for (int d = 0; d < MDd; ++d) s += ql[d]*Mem[tid*MDd + d];
        sm[tid] = s;
    }
    __syncthreads();
    if (tid == 0){
        float mx = -1e30f; int am = 0;
        for (int m = 0; m < Mm; ++m) if (sm[m] > mx){ mx = sm[m]; am = m; }
        float ssum = 0.f;
        for (int m = 0; m < Mm; ++m){ float e = expf(sm[m]-mx); sm[m] = e; ssum += e; }
        stats[0] = 1.f/ssum; smind = am;
    }
    __syncthreads();
    float inv = stats[0]; int am = smind;
    float val = 0.f;
    for (int m = 0; m < Mm; ++m) val += sm[m]*inv*Mem[m*MDd + tid];
    outv[bn*MDd + tid] = val;
    outp[bn*MDd + tid] = Mem[am*MDd + tid];
    hdec[(size_t)rb*DECHd + tid]       = hl[tid];
    hdec[(size_t)rb*DECHd + 64 + tid]  = hl[tid + 64];
    hdec[(size_t)rb*DECHd + 128 + tid] = val;
    if (tid == 0) ind0[rb] = am;
}

__global__ void neg_kernel(const float* __restrict__ Mem, float* __restrict__ outn)
{
    size_t idx = (size_t)blockIdx.x*256 + threadIdx.x;
    outn[idx] = Mem[idx % (Mm*MDd)];
}

__global__ void mask_kernel(const int* __restrict__ ind0, float* __restrict__ outm)
{
    size_t idx = (size_t)blockIdx.x*256 + threadIdx.x;
    int m   = (int)(idx % Mm);
    size_t bn = idx / Mm;
    int n = (int)(bn % Nn);
    int b = (int)(bn / Nn);
    int rb = n*Bb + b;
    outm[idx] = (m != ind0[rb]) ? 1.f : 0.f;
}

__global__ __launch_bounds__(256) void proj_kernel(const float* __restrict__ h,
                                                   const float* __restrict__ pw,
                                                   const float* __restrict__ pb,
                                                   float* __restrict__ go,
                                                   float* __restrict__ out0, int t)
{
    int rb = blockIdx.x*4 + (threadIdx.x >> 6);
    int lane = threadIdx.x & 63;
    float s = 0.f;
    #pragma unroll
    for (int r = 0; r < 3; ++r){
        int i = lane + r*64;
        s += h[(size_t)rb*DECHd + i]*pw[i];
    }
    #pragma unroll
    for (int off = 32; off > 0; off >>= 1) s += __shfl_down(s, off, 64);
    if (lane == 0){
        float v = s + pb[0];
        go[rb] = v;
        int n = rb / Bb, b = rb % Bb;
        out0[((size_t)b*HORt + t)*Nn + n] = v;
    }
}

// ---------------------------------------------------------------------------
extern "C" void kernel_launch(void* const* d_in, const int* in_sizes, int n_in,
                              void* d_out, int out_size, void* d_ws, size_t ws_size,
                              hipStream_t stream)
{
    const float* x    = (const float*)d_in[0];
    const float* ycov = (const float*)d_in[1];
    const float* emb  = (const float*)d_in[2];
    const float* Mem  = (const float*)d_in[3];
    const float* Wq   = (const float*)d_in[4];
    const float* eWg  = (const float*)d_in[5];
    const float* ebg  = (const float*)d_in[6];
    const float* eWu  = (const float*)d_in[7];
    const float* ebu  = (const float*)d_in[8];
    const float* dWg  = (const float*)d_in[9];
    const float* dbg  = (const float*)d_in[10];
    const float* dWu  = (const float*)d_in[11];
    const float* dbu  = (const float*)d_in[12];
    const float* pW   = (const float*)d_in[13];
    const float* pb   = (const float*)d_in[14];

    float* out        = (float*)d_out;
    float* out_output = out;
    float* out_value  = out + 786432;
    float* out_query  = out + 4980736;
    float* out_pos    = out + 9175040;
    float* out_neg    = out + 13369344;          // 83,886,080 floats (335.5 MB)
    float* out_mask   = out + 97255424;

    // determinism hammer (r7-verified): identical state every call
    hipMemsetAsync(d_out, 0, (size_t)out_size * 4, stream);

    // ---- out_neg scratch, time-shared ----
    ushort* catEh  = (ushort*)out_neg;                       // 31,457,280
    ushort* catEl  = catEh + 31457280;                       // 31,457,280
    ushort* catETh = catEl + 31457280;                       // 10,485,760
    ushort* catETl = catETh + 10485760;                      // 10,485,760
    float*  zrE    = (float*)(catETl + 10485760);            // 16,777,216 fp32
    bf16*  cat0  = (bf16*)out_neg;                           // 14,680,064
    bf16*  cat1  = cat0 + 14680064;
    bf16*  cat2  = cat1 + 14680064;
    bf16*  cat0T = cat2 + 14680064;                          // 14,680,064
    bf16*  zrb   = cat0T + 14680064;                         // 25,165,824

    // ---- d_ws layout (~107 MB; ws >= 173 MB, r3) ----
    const size_t NEED = 106979328;
    if (ws_size < NEED){
        ws_probe_kernel<<<3072, 256, 0, stream>>>(out_output, (float)(ws_size >> 20));
        return;
    }
    float*  Sf    = (float*)d_ws;                // 1,048,576 f32
    float*  T2f   = Sf + 1048576;                // 1,048,576 f32
    ushort* Sh    = (ushort*)(T2f + 1048576);    // [Sh|T2h] stacked hi
    ushort* T2h   = Sh  + 1048576;
    ushort* Sl    = T2h + 1048576;               // [Sl|T2l] stacked lo
    ushort* T2l   = Sl  + 1048576;
    bf16*   Sb    = (bf16*)(T2l + 1048576);      // [Sb|T2b] stacked bf16
    bf16*   T2b   = Sb + 1048576;
    ushort* wgETh = (ushort*)(T2b + 1048576);    // 3*256*160 = 122,880
    ushort* wgETl = wgETh + 122880;
    ushort* wuETh = wgETl + 122880;              // 3*128*160 = 61,440
    ushort* wuETl = wuETh + 61440;
    bf16*   wgDT  = (bf16*)(wuETl + 61440);      // 3*384*224 = 258,048
    bf16*   wuDT  = wgDT + 258048;               // 3*256*224 = 172,032
    float*  henc  = (float*)(wuDT + 172032);     // 8,388,608 f32
    float*  hdec  = henc + 8388608;              // 12,582,912 f32
    float*  go    = hdec + 12582912;             // 65,536 f32
    int*    ind0  = (int*)(go + 65536);          // 65,536 int

    hipMemsetAsync(henc, 0, (size_t)8388608*4, stream);
    hipMemsetAsync(go,   0, (size_t)65536*4,   stream);

    supports_kernel<<<Nn, 256, 0, stream>>>(emb, Sf);
    t2_gemm<<<dim3(16,16), 256, 0, stream>>>(Sf, T2f);
    conv_split<<<4096, 256, 0, stream>>>(Sf,  Sh,  Sl,  4096.f);
    conv_split<<<4096, 256, 0, stream>>>(T2f, T2h, T2l, 4096.f);
    conv_f2b<<<4096, 256, 0, stream>>>(Sf,  Sb);
    conv_f2b<<<4096, 256, 0, stream>>>(T2f, T2b);
    conv_w_split_T<<<480, 256, 0, stream>>>(eWg, wgETh, wgETl, 129, CPe, 256);
    conv_w_split_T<<<240, 256, 0, stream>>>(eWu, wuETh, wuETl, 129, CPe, 128);
    conv_w_T<<<1008, 256, 0, stream>>>(dWg, wgDT, 194, CPd, 384, 384);
    conv_w_T<<<672,  256, 0, stream>>>(dWu, wuDT, 194, CPd, 192, 256);

    const size_t SL = (size_t)65536*CPe;         // 10,485,760 = 1024*JPe (contig!)

    // -------- encoder: 12 steps, split-fp16 MFMA; BM=256 GCN --------
    for (int t = 0; t < Tt; ++t){
        build_encT<1><<<dim3(JPe/64, 16), 256, 0, stream>>>(
            x, henc, nullptr, catEh, catEl, catETh, catETl, t);
        mfma_split_gcn<<<dim3(JPe/128, 8), 256, 0, stream>>>(
            Sh, Sl, catETh, catETl, Nn, Nn, Nn,
            catEh + SL, catEl + SL, JPe);
        mfma_split<1><<<dim3(2, 512), 256, 0, stream>>>(
            catEh, catEl, catEh + SL, catEl + SL, catEh + 2*SL, catEl + 2*SL,
            wgETh, wgETl, wgETh + 40960, wgETl + 40960, wgETh + 81920, wgETl + 81920,
            3, CPe, CPe, CPe,
            nullptr, nullptr, 0, 256, zrE, ZRE, ebg, nullptr, nullptr, 0);
        build_encT<2><<<dim3(JPe/64, 16), 256, 0, stream>>>(
            x, henc, zrE, catEh, catEl, catETh, catETl, t);
        mfma_split_gcn<<<dim3(JPe/128, 8), 256, 0, stream>>>(
            Sh, Sl, catETh, catETl, Nn, Nn, Nn,
            catEh + SL, catEl + SL, JPe);
        mfma_split<2><<<dim3(1, 512), 256, 0, stream>>>(
            catEh, catEl, catEh + SL, catEl + SL, catEh + 2*SL, catEl + 2*SL,
            wuETh, wuETl, wuETh + 20480, wuETl + 20480, wuETh + 40960, wuETl + 40960,
            3, CPe, CPe, CPe,
            nullptr, nullptr, 0, 128, nullptr, ZRE, ebu, zrE, henc, 128);
    }

    // -------- attention (fp32 scores -> exact argmax) --------
    attn_kernel<<<65536, 64, 0, stream>>>(henc, Wq, Mem, hdec, ind0,
                                          out_value, out_query, out_pos);

    const ushort* Su   = (const ushort*)Sb;      // stacked [Sb|T2b]
    const ushort* c0u  = (const ushort*)cat0;
    const ushort* c1u  = (const ushort*)cat1;
    const ushort* c2u  = (const ushort*)cat2;
    const ushort* c0Tu = (const ushort*)cat0T;

    // -------- decoder: 12 steps, bf16 MFMA; BM=256 GCN --------
    for (int t = 0; t < HORt; ++t){
        build_decT<1><<<dim3(JPd/64, 16), 256, 0, stream>>>(
            go, ycov, hdec, nullptr, cat0, cat0T, t);
        mfma_gemm_gcn<<<dim3(JPd/128, 8), 256, 0, stream>>>(
            Su, c0Tu, Nn, Nn, Nn, cat1, JPd);
        mfma_gemm<1><<<dim3(3, 512), 256, 0, stream>>>(
            c0u, c1u, c2u,
            (const ushort*)wgDT, (const ushort*)(wgDT + 86016), (const ushort*)(wgDT + 172032),
            3, CPd, CPd, CPd, zrb, LDZR, 384, dbg, nullptr, nullptr, 0);
        build_decT<2><<<dim3(JPd/64, 16), 256, 0, stream>>>(
            go, ycov, hdec, zrb, cat0, cat0T, t);
        mfma_gemm_gcn<<<dim3(JPd/128, 8), 256, 0, stream>>>(
            Su, c0Tu, Nn, Nn, Nn, cat1, JPd);
        mfma_gemm<2><<<dim3(2, 512), 256, 0, stream>>>(
            c0u, c1u, c2u,
            (const ushort*)wuDT, (const ushort*)(wuDT + 57344), (const ushort*)(wuDT + 114688),
            3, CPd, CPd, CPd, nullptr, 0, 192, dbu, zrb, hdec, 192);
        proj_kernel<<<16384, 256, 0, stream>>>(hdec, pW, pb, go, out_output, t);
    }

    // -------- aux outputs LAST --------
    neg_kernel<<<327680, 256, 0, stream>>>(Mem, out_neg);
    mask_kernel<<<5120, 256, 0, stream>>>(ind0, out_mask);
}

// Round 16
// 11015.884 us; speedup vs baseline: 1.3224x; 1.3224x over previous
//
#include <hip/hip_runtime.h>
#include <hip/hip_bf16.h>

typedef __hip_bfloat16 bf16;
typedef __attribute__((ext_vector_type(8))) short short8;
typedef __attribute__((ext_vector_type(8))) _Float16 half8;
typedef __attribute__((ext_vector_type(4))) float f32x4;
typedef __attribute__((ext_vector_type(4))) int   int4v;

#define Bb   64
#define Tt   12
#define Nn   1024
#define HORt 12
#define Hh   128
#define Ee   16
#define Mm   20
#define MDd  64
#define DECHd 192
#define CPe  160               // padded enc cat width (129 -> 160)
#define JPe  (Bb*CPe)          // 10240
#define CPd  224               // padded dec cat width (194 -> 224)
#define JPd  (Bb*CPd)          // 14336
#define LDZR 384               // decoder zr stride (bf16)
#define ZRE  256               // encoder zr stride (fp32)

#define INV_SCALE (1.f/4096.f)

// LDS chunk swizzle (2-way-max; XOR involution, r12-verified bit-identical)
#define SWZ(row) (((row) >> 1) & 3)

// async global->LDS: wave-uniform LDS base + lane*16; per-lane global src.
#define GLOAD_LDS16(gp, lp) \
    __builtin_amdgcn_global_load_lds((const __attribute__((address_space(1))) void*)(gp), \
                                     (__attribute__((address_space(3))) void*)(lp), 16, 0, 0)

__device__ __forceinline__ float b2f(bf16 v){ return __bfloat162float(v); }
__device__ __forceinline__ bf16  f2b(float v){ return __float2bfloat16(v); }
__device__ __forceinline__ void splitf16(float v, ushort& hi, ushort& lo){
    _Float16 h = (_Float16)v;
    _Float16 l = (_Float16)(v - (float)h);
    hi = __builtin_bit_cast(ushort, h);
    lo = __builtin_bit_cast(ushort, l);
}

// XCD-chunked GCN block remap: flat bid -> (j_tile, m_tile). All 16 m-tiles
// of one j-tile land on ONE XCD, temporally adjacent -> B panel L2-hot.
// Bijective for jt % 8 == 0, 16 m-tiles. Pure work permutation.
__device__ __forceinline__ void gcn_remap(int bid, int jt, int& j, int& m){
    int xcd  = bid & 7;
    int slot = bid >> 3;
    j = xcd * (jt >> 3) + (slot >> 4);
    m = slot & 15;
}

// ---------------------------------------------------------------------------
__global__ void ws_probe_kernel(float* __restrict__ out, float val)
{
    size_t i = (size_t)blockIdx.x*256 + threadIdx.x;
    out[i] = val;
}

__global__ void conv_f2b(const float* __restrict__ src, bf16* __restrict__ dst)
{
    size_t i = (size_t)blockIdx.x*256 + threadIdx.x;
    dst[i] = f2b(src[i]);
}

__global__ void conv_split(const float* __restrict__ src, ushort* __restrict__ hi,
                           ushort* __restrict__ lo, float scale)
{
    size_t i = (size_t)blockIdx.x*256 + threadIdx.x;
    splitf16(src[i]*scale, hi[i], lo[i]);
}

// encoder weights TRANSPOSED: fp32 (3*C x No) -> f16 hi/lo [3][No][CP] x256
__global__ void conv_w_split_T(const float* __restrict__ W, ushort* __restrict__ hi,
                               ushort* __restrict__ lo, int C, int CP, int No)
{
    int idx = blockIdx.x*256 + threadIdx.x;
    if (idx >= 3*No*CP) return;
    int km = idx / (No*CP);
    int r  = idx % (No*CP);
    int o  = r / CP, k = r % CP;
    float v = (k < C) ? W[(size_t)(km*C + k)*No + o]*256.f : 0.f;
    splitf16(v, hi[idx], lo[idx]);
}

// decoder weights TRANSPOSED: fp32 (3*C x No) -> bf16 [3][NoP][CP]
__global__ void conv_w_T(const float* __restrict__ W, bf16* __restrict__ dst,
                         int C, int CP, int No, int NoP)
{
    int idx = blockIdx.x*256 + threadIdx.x;
    if (idx >= 3*NoP*CP) return;
    int km = idx / (NoP*CP);
    int r  = idx % (NoP*CP);
    int o  = r / CP, k = r % CP;
    dst[idx] = (k < C && o < No) ? f2b(W[(size_t)(km*C + k)*No + o]) : f2b(0.f);
}

// ---------------------------------------------------------------------------
// supports = softmax(relu(emb @ emb^T), axis=1)  (fp32, verified)
// ---------------------------------------------------------------------------
__global__ __launch_bounds__(256) void supports_kernel(const float* __restrict__ emb,
                                                       float* __restrict__ S)
{
    int n = blockIdx.x;
    __shared__ float row[Nn];
    __shared__ float en[Ee];
    __shared__ float red[256];
    int tid = threadIdx.x;
    if (tid < Ee) en[tid] = emb[n*Ee + tid];
    __syncthreads();
    float lmax = -1e30f;
    for (int j = tid; j < Nn; j += 256){
        float d = 0.f;
        #pragma unroll
        for (int e = 0; e < Ee; ++e) d += en[e]*emb[j*Ee + e];
        d = d > 0.f ? d : 0.f;
        row[j] = d;
        lmax = fmaxf(lmax, d);
    }
    red[tid] = lmax; __syncthreads();
    for (int s = 128; s > 0; s >>= 1){ if (tid < s) red[tid] = fmaxf(red[tid], red[tid+s]); __syncthreads(); }
    float mx = red[0]; __syncthreads();
    float lsum = 0.f;
    for (int j = tid; j < Nn; j += 256){ float e = expf(row[j]-mx); row[j] = e; lsum += e; }
    red[tid] = lsum; __syncthreads();
    for (int s = 128; s > 0; s >>= 1){ if (tid < s) red[tid] += red[tid+s]; __syncthreads(); }
    float inv = 1.f/red[0];
    for (int j = tid; j < Nn; j += 256) S[n*Nn + j] = row[j]*inv;
}

// ---------------------------------------------------------------------------
// T2 = 2*S@S - I   (fp32, verified)
// ---------------------------------------------------------------------------
__global__ __launch_bounds__(256) void t2_gemm(const float* __restrict__ S,
                                               float* __restrict__ T2)
{
    int n0 = blockIdx.y*64, j0 = blockIdx.x*64;
    __shared__ float As[16][65];
    __shared__ float Xs[16][65];
    int tid = threadIdx.x; int tx = tid & 15, ty = tid >> 4;
    float acc[4][4] = {};
    for (int k0 = 0; k0 < Nn; k0 += 16){
        #pragma unroll
        for (int r = 0; r < 4; ++r){
            int idx = tid + r*256;
            int ar = idx >> 4, ak = idx & 15;
            As[ak][ar] = S[(n0+ar)*Nn + k0+ak];
        }
        #pragma unroll
        for (int r = 0; r < 4; ++r){
            int idx = tid + r*256;
            int xm = idx >> 6, xj = idx & 63;
            Xs[xm][xj] = S[(k0+xm)*Nn + j0+xj];
        }
        __syncthreads();
        #pragma unroll
        for (int kk = 0; kk < 16; ++kk){
            float a[4], xv[4];
            #pragma unroll
            for (int i = 0; i < 4; ++i) a[i]  = As[kk][ty*4+i];
            #pragma unroll
            for (int j = 0; j < 4; ++j) xv[j] = Xs[kk][tx*4+j];
            #pragma unroll
            for (int i = 0; i < 4; ++i)
                #pragma unroll
                for (int j = 0; j < 4; ++j) acc[i][j] += a[i]*xv[j];
        }
        __syncthreads();
    }
    #pragma unroll
    for (int i = 0; i < 4; ++i){
        int n = n0 + ty*4 + i;
        #pragma unroll
        for (int j = 0; j < 4; ++j){
            int c = j0 + tx*4 + j;
            T2[n*Nn + c] = 2.f*acc[i][j] - (n == c ? 1.f : 0.f);
        }
    }
}

// ---------------------------------------------------------------------------
// FUSED encoder cat builder + transpose (r14-verified)
// ---------------------------------------------------------------------------
template<int PHASE>
__global__ __launch_bounds__(256) void build_encT(
    const float* __restrict__ x, const float* __restrict__ h,
    const float* __restrict__ zre,
    ushort* __restrict__ chi, ushort* __restrict__ clo,
    ushort* __restrict__ cThi, ushort* __restrict__ cTlo, int t)
{
    __shared__ ushort th[64][66];
    __shared__ ushort tl[64][66];
    int j0 = blockIdx.x*64, n0 = blockIdx.y*64;
    for (int i = threadIdx.x; i < 4096; i += 256){
        int r = i >> 6, cc = i & 63;
        int n = n0 + r, j = j0 + cc;
        int b = j / CPe, c = j % CPe;
        size_t rb = (size_t)n*64 + b;
        float v;
        if (c == 0)       v = x[((size_t)b*Tt + t)*Nn + n];
        else if (c < 129) v = (PHASE == 1) ? h[rb*Hh + (c-1)]
                                           : zre[rb*ZRE + (c-1)] * h[rb*Hh + (c-1)];
        else              v = 0.f;
        ushort hi, lo; splitf16(v*16.f, hi, lo);
        th[r][cc] = hi; tl[r][cc] = lo;
        chi[(size_t)n*JPe + j] = hi;
        clo[(size_t)n*JPe + j] = lo;
    }
    __syncthreads();
    for (int i = threadIdx.x; i < 4096; i += 256){
        int cc = i >> 6, r = i & 63;
        size_t d = (size_t)(j0+cc)*1024 + n0 + r;
        cThi[d] = th[r][cc];
        cTlo[d] = tl[r][cc];
    }
}

// ---------------------------------------------------------------------------
// FUSED decoder cat builder + transpose (r14-verified)
// ---------------------------------------------------------------------------
template<int PHASE>
__global__ __launch_bounds__(256) void build_decT(
    const float* __restrict__ go, const float* __restrict__ yc,
    const float* __restrict__ h, const bf16* __restrict__ zrb,
    bf16* __restrict__ cat, bf16* __restrict__ catT, int t)
{
    __shared__ ushort tt[64][66];
    int j0 = blockIdx.x*64, n0 = blockIdx.y*64;
    for (int i = threadIdx.x; i < 4096; i += 256){
        int r = i >> 6, cc = i & 63;
        int n = n0 + r, j = j0 + cc;
        int b = j / CPd, c = j % CPd;
        size_t rb = (size_t)n*64 + b;
        float v;
        if (c == 0)       v = go[rb];
        else if (c == 1)  v = yc[((size_t)b*HORt + t)*Nn + n];
        else if (c < 194) v = (PHASE == 1) ? h[rb*DECHd + (c-2)]
                                           : b2f(zrb[rb*LDZR + (c-2)]) * h[rb*DECHd + (c-2)];
        else              v = 0.f;
        bf16 bv = f2b(v);
        tt[r][cc] = __builtin_bit_cast(ushort, bv);
        cat[(size_t)n*JPd + j] = bv;
    }
    __syncthreads();
    for (int i = threadIdx.x; i < 4096; i += 256){
        int cc = i >> 6, r = i & 63;
        bf16 bv = __builtin_bit_cast(bf16, tt[r][cc]);
        catT[(size_t)(j0+cc)*1024 + n0 + r] = bv;
    }
}

// ---------------------------------------------------------------------------
// split-fp16 3-pass MFMA GEMM, 128^2 (r14-verified math).
// jt > 0: flat 1-D grid with XCD-chunked (j,m) remap (GCN). jt == 0: legacy 2-D.
// ---------------------------------------------------------------------------
template<int EPI>
__global__ __launch_bounds__(256) void mfma_split(
    const ushort* __restrict__ Ah0, const ushort* __restrict__ Al0,
    const ushort* __restrict__ Ah1, const ushort* __restrict__ Al1,
    const ushort* __restrict__ Ah2, const ushort* __restrict__ Al2,
    const ushort* __restrict__ BhT0, const ushort* __restrict__ BlT0,
    const ushort* __restrict__ BhT1, const ushort* __restrict__ BlT1,
    const ushort* __restrict__ BhT2, const ushort* __restrict__ BlT2,
    int nmat, int Ksz, int lda, int ldbT,
    ushort* __restrict__ OutHi, ushort* __restrict__ OutLo, int ldc, int Ncols,
    float* __restrict__ OutF, int ldo,
    const float* __restrict__ bias, const float* __restrict__ zrf,
    float* __restrict__ hbuf, int Hd, int jt)
{
    __shared__ short Ah_s[128*32];
    __shared__ short Al_s[128*32];
    __shared__ short Bh_s[128*32];
    __shared__ short Bl_s[128*32];
    int tid = threadIdx.x;
    int bx, by;
    if (jt > 0){ gcn_remap(blockIdx.x, jt, bx, by); }
    else       { bx = blockIdx.x; by = blockIdx.y; }
    int m0 = by * 128;
    int n0 = bx * 128;
    int wave = tid >> 6, lane = tid & 63;
    int wr = wave >> 1, wc = wave & 1;
    int lr = lane & 15, lk8 = lane >> 4;

    f32x4 acc[4][4];
    #pragma unroll
    for (int i = 0; i < 4; ++i)
        #pragma unroll
        for (int j = 0; j < 4; ++j) acc[i][j] = (f32x4){0.f,0.f,0.f,0.f};

    const ushort* Ahs[3] = {Ah0, Ah1, Ah2};
    const ushort* Als[3] = {Al0, Al1, Al2};
    const ushort* Bhs[3] = {BhT0, BhT1, BhT2};
    const ushort* Bls[3] = {BlT0, BlT1, BlT2};

    int wbase = wave * 1024;

    for (int km = 0; km < nmat; ++km){
        const ushort* Agh = Ahs[km]; const ushort* Agl = Als[km];
        const ushort* Bgh = Bhs[km]; const ushort* Bgl = Bls[km];
        for (int k0 = 0; k0 < Ksz; k0 += 32){
            #pragma unroll
            for (int r = 0; r < 2; ++r){
                int i = tid + r*256;
                int row = i >> 2, q = i & 3;
                int sq = q ^ SWZ(row);
                size_t soA = (size_t)(m0+row)*lda  + k0 + sq*8;
                size_t soB = (size_t)(n0+row)*ldbT + k0 + sq*8;
                int lofs = r*4096 + wbase;
                GLOAD_LDS16(Agh + soA, (char*)Ah_s + lofs);
                GLOAD_LDS16(Agl + soA, (char*)Al_s + lofs);
                GLOAD_LDS16(Bgh + soB, (char*)Bh_s + lofs);
                GLOAD_LDS16(Bgl + soB, (char*)Bl_s + lofs);
            }
            __syncthreads();
            half8 ah[4], al[4], bh[4], bl[4];
            #pragma unroll
            for (int mi = 0; mi < 4; ++mi){
                int row = wr*64 + mi*16 + lr;
                int off = row*64 + ((lk8 ^ SWZ(row)) << 4);
                ah[mi] = *(const half8*)((const char*)Ah_s + off);
                al[mi] = *(const half8*)((const char*)Al_s + off);
            }
            #pragma unroll
            for (int ni = 0; ni < 4; ++ni){
                int col = wc*64 + ni*16 + lr;
                int off = col*64 + ((lk8 ^ SWZ(col)) << 4);
                bh[ni] = *(const half8*)((const char*)Bh_s + off);
                bl[ni] = *(const half8*)((const char*)Bl_s + off);
            }
            #pragma unroll
            for (int mi = 0; mi < 4; ++mi)
                #pragma unroll
                for (int ni = 0; ni < 4; ++ni){
                    acc[mi][ni] = __builtin_amdgcn_mfma_f32_16x16x32_f16(ah[mi], bh[ni], acc[mi][ni], 0, 0, 0);
                    acc[mi][ni] = __builtin_amdgcn_mfma_f32_16x16x32_f16(ah[mi], bl[ni], acc[mi][ni], 0, 0, 0);
                    acc[mi][ni] = __builtin_amdgcn_mfma_f32_16x16x32_f16(al[mi], bh[ni], acc[mi][ni], 0, 0, 0);
                }
            __syncthreads();
        }
    }

    int rbase = lk8 * 4;
    #pragma unroll
    for (int mi = 0; mi < 4; ++mi){
        #pragma unroll
        for (int ni = 0; ni < 4; ++ni){
            int gn = n0 + wc*64 + ni*16 + lr;
            if (gn >= Ncols) continue;
            #pragma unroll
            for (int rg = 0; rg < 4; ++rg){
                int gm = m0 + wr*64 + mi*16 + rbase + rg;
                float v = acc[mi][ni][rg] * INV_SCALE;
                if (EPI == 0){
                    ushort h, l;
                    splitf16(v, h, l);
                    OutHi[(size_t)gm*ldc + gn] = h;
                    OutLo[(size_t)gm*ldc + gn] = l;
                } else if (EPI == 1){
                    v += bias[gn];
                    OutF[(size_t)gm*ldo + gn] = 1.f/(1.f + expf(-v));
                } else {
                    float hc = tanhf(v + bias[gn]);
                    float rr = zrf[(size_t)gm*ldo + Hd + gn];
                    float ho = hbuf[(size_t)gm*Hd + gn];
                    hbuf[(size_t)gm*Hd + gn] = rr*ho + (1.f-rr)*hc;
                }
            }
        }
    }
}

// ---------------------------------------------------------------------------
// decoder bf16 MFMA GEMM, 128^2 (r14-verified math; jt remap as above)
// ---------------------------------------------------------------------------
template<int EPI>
__global__ __launch_bounds__(256) void mfma_gemm(
    const ushort* __restrict__ A0, const ushort* __restrict__ A1, const ushort* __restrict__ A2,
    const ushort* __restrict__ BT0, const ushort* __restrict__ BT1, const ushort* __restrict__ BT2,
    int nmat, int Ksz, int lda, int ldbT,
    bf16* __restrict__ Cout, int ldc, int Ncols,
    const float* __restrict__ bias,
    const bf16* __restrict__ zr, float* __restrict__ hbuf, int Hd, int jt)
{
    __shared__ short As[128*32];
    __shared__ short Bs[128*32];
    int tid = threadIdx.x;
    int bx, by;
    if (jt > 0){ gcn_remap(blockIdx.x, jt, bx, by); }
    else       { bx = blockIdx.x; by = blockIdx.y; }
    int m0 = by * 128;
    int n0 = bx * 128;
    int wave = tid >> 6, lane = tid & 63;
    int wr = wave >> 1, wc = wave & 1;
    int lr = lane & 15, lk8 = lane >> 4;

    f32x4 acc[4][4];
    #pragma unroll
    for (int i = 0; i < 4; ++i)
        #pragma unroll
        for (int j = 0; j < 4; ++j) acc[i][j] = (f32x4){0.f,0.f,0.f,0.f};

    const ushort* Aps[3] = {A0, A1, A2};
    const ushort* Bps[3] = {BT0, BT1, BT2};

    int wbase = wave * 1024;

    for (int km = 0; km < nmat; ++km){
        const ushort* Ag = Aps[km];
        const ushort* Bg = Bps[km];
        for (int k0 = 0; k0 < Ksz; k0 += 32){
            #pragma unroll
            for (int r = 0; r < 2; ++r){
                int i = tid + r*256;
                int row = i >> 2, q = i & 3;
                int sq = q ^ SWZ(row);
                size_t soA = (size_t)(m0+row)*lda  + k0 + sq*8;
                size_t soB = (size_t)(n0+row)*ldbT + k0 + sq*8;
                int lofs = r*4096 + wbase;
                GLOAD_LDS16(Ag + soA, (char*)As + lofs);
                GLOAD_LDS16(Bg + soB, (char*)Bs + lofs);
            }
            __syncthreads();
            short8 af[4], bfv[4];
            #pragma unroll
            for (int mi = 0; mi < 4; ++mi){
                int row = wr*64 + mi*16 + lr;
                int off = row*64 + ((lk8 ^ SWZ(row)) << 4);
                af[mi] = *(const short8*)((const char*)As + off);
            }
            #pragma unroll
            for (int ni = 0; ni < 4; ++ni){
                int col = wc*64 + ni*16 + lr;
                int off = col*64 + ((lk8 ^ SWZ(col)) << 4);
                bfv[ni] = *(const short8*)((const char*)Bs + off);
            }
            #pragma unroll
            for (int mi = 0; mi < 4; ++mi)
                #pragma unroll
                for (int ni = 0; ni < 4; ++ni)
                    acc[mi][ni] = __builtin_amdgcn_mfma_f32_16x16x32_bf16(
                                      af[mi], bfv[ni], acc[mi][ni], 0, 0, 0);
            __syncthreads();
        }
    }

    int rbase = lk8 * 4;
    #pragma unroll
    for (int mi = 0; mi < 4; ++mi){
        #pragma unroll
        for (int ni = 0; ni < 4; ++ni){
            int gn = n0 + wc*64 + ni*16 + lr;
            if (gn >= Ncols) continue;
            #pragma unroll
            for (int rg = 0; rg < 4; ++rg){
                int gm = m0 + wr*64 + mi*16 + rbase + rg;
                float v = acc[mi][ni][rg];
                if (EPI == 0){
                    Cout[(size_t)gm*ldc + gn] = f2b(v);
                } else if (EPI == 1){
                    v += bias[gn];
                    Cout[(size_t)gm*ldc + gn] = f2b(1.f/(1.f + expf(-v)));
                } else {
                    float hc = tanhf(v + bias[gn]);
                    float rr = b2f(zr[(size_t)gm*LDZR + Hd + gn]);
                    float ho = hbuf[(size_t)gm*Hd + gn];
                    hbuf[(size_t)gm*Hd + gn] = rr*ho + (1.f-rr)*hc;
                }
            }
        }
    }
}

// ---------------------------------------------------------------------------
// attention (fp32, verified)
// ---------------------------------------------------------------------------
__global__ __launch_bounds__(64) void attn_kernel(const float* __restrict__ hT,
                                                  const float* __restrict__ Wq,
                                                  const float* __restrict__ Mem,
                                                  float* __restrict__ hdec,
                                                  int* __restrict__ ind0,
                                                  float* __restrict__ outv,
                                                  float* __restrict__ outq,
                                                  float* __restrict__ outp)
{
    int rb = blockIdx.x; int n = rb / Bb, b = rb % Bb;
    int tid = threadIdx.x;
    __shared__ float hl[Hh];
    __shared__ float ql[MDd];
    __shared__ float sm[Mm];
    __shared__ float stats[2];
    __shared__ int   smind;
    hl[tid]      = hT[(size_t)rb*Hh + tid];
    hl[tid + 64] = hT[(size_t)rb*Hh + tid + 64];
    __syncthreads();
    float q = 0.f;
    for (int hh = 0; hh < Hh; ++hh) q += hl[hh]*Wq[hh*MDd + tid];
    ql[tid] = q;
    size_t bn = (size_t)b*Nn + n;
    outq[bn*MDd + tid] = q;
    __syncthreads();
    if (tid < Mm){
        float s = 0.f;
        for (int d = 0; d < MDd; ++d) s += ql[d]*Mem[tid*MDd + d];
        sm[tid] = s;
    }
    __syncthreads();
    if (tid == 0){
        float mx = -1e30f; int am = 0;
        for (int m = 0; m < Mm; ++m) if (sm[m] > mx){ mx = sm[m]; am = m; }
        float ssum = 0.f;
        for (int m = 0; m < Mm; ++m){ float e = expf(sm[m]-mx); sm[m] = e; ssum += e; }
        stats[0] = 1.f/ssum; smind = am;
    }
    __syncthreads();
    float inv = stats[0]; int am = smind;
    float val = 0.f;
    for (int m = 0; m < Mm; ++m) val += sm[m]*inv*Mem[m*MDd + tid];
    outv[bn*MDd + tid] = val;
    outp[bn*MDd + tid] = Mem[am*MDd + tid];
    hdec[(size_t)rb*DECHd + tid]       = hl[tid];
    hdec[(size_t)rb*DECHd + 64 + tid]  = hl[tid + 64];
    hdec[(size_t)rb*DECHd + 128 + tid] = val;
    if (tid == 0) ind0[rb] = am;
}

__global__ void neg_kernel(const float* __restrict__ Mem, float* __restrict__ outn)
{
    size_t idx = (size_t)blockIdx.x*256 + threadIdx.x;
    outn[idx] = Mem[idx % (Mm*MDd)];
}

__global__ void mask_kernel(const int* __restrict__ ind0, float* __restrict__ outm)
{
    size_t idx = (size_t)blockIdx.x*256 + threadIdx.x;
    int m   = (int)(idx % Mm);
    size_t bn = idx / Mm;
    int n = (int)(bn % Nn);
    int b = (int)(bn / Nn);
    int rb = n*Bb + b;
    outm[idx] = (m != ind0[rb]) ? 1.f : 0.f;
}

__global__ __launch_bounds__(256) void proj_kernel(const float* __restrict__ h,
                                                   const float* __restrict__ pw,
                                                   const float* __restrict__ pb,
                                                   float* __restrict__ go,
                                                   float* __restrict__ out0, int t)
{
    int rb = blockIdx.x*4 + (threadIdx.x >> 6);
    int lane = threadIdx.x & 63;
    float s = 0.f;
    #pragma unroll
    for (int r = 0; r < 3; ++r){
        int i = lane + r*64;
        s += h[(size_t)rb*DECHd + i]*pw[i];
    }
    #pragma unroll
    for (int off = 32; off > 0; off >>= 1) s += __shfl_down(s, off, 64);
    if (lane == 0){
        float v = s + pb[0];
        go[rb] = v;
        int n = rb / Bb, b = rb % Bb;
        out0[((size_t)b*HORt + t)*Nn + n] = v;
    }
}

// ---------------------------------------------------------------------------
extern "C" void kernel_launch(void* const* d_in, const int* in_sizes, int n_in,
                              void* d_out, int out_size, void* d_ws, size_t ws_size,
                              hipStream_t stream)
{
    const float* x    = (const float*)d_in[0];
    const float* ycov = (const float*)d_in[1];
    const float* emb  = (const float*)d_in[2];
    const float* Mem  = (const float*)d_in[3];
    const float* Wq   = (const float*)d_in[4];
    const float* eWg  = (const float*)d_in[5];
    const float* ebg  = (const float*)d_in[6];
    const float* eWu  = (const float*)d_in[7];
    const float* ebu  = (const float*)d_in[8];
    const float* dWg  = (const float*)d_in[9];
    const float* dbg  = (const float*)d_in[10];
    const float* dWu  = (const float*)d_in[11];
    const float* dbu  = (const float*)d_in[12];
    const float* pW   = (const float*)d_in[13];
    const float* pb   = (const float*)d_in[14];

    float* out        = (float*)d_out;
    float* out_output = out;
    float* out_value  = out + 786432;
    float* out_query  = out + 4980736;
    float* out_pos    = out + 9175040;
    float* out_neg    = out + 13369344;          // 83,886,080 floats (335.5 MB)
    float* out_mask   = out + 97255424;

    // determinism hammer (r7-verified): identical state every call
    hipMemsetAsync(d_out, 0, (size_t)out_size * 4, stream);

    // ---- out_neg scratch, time-shared ----
    ushort* catEh  = (ushort*)out_neg;                       // 31,457,280
    ushort* catEl  = catEh + 31457280;                       // 31,457,280
    ushort* catETh = catEl + 31457280;                       // 10,485,760
    ushort* catETl = catETh + 10485760;                      // 10,485,760
    float*  zrE    = (float*)(catETl + 10485760);            // 16,777,216 fp32
    bf16*  cat0  = (bf16*)out_neg;                           // 14,680,064
    bf16*  cat1  = cat0 + 14680064;
    bf16*  cat2  = cat1 + 14680064;
    bf16*  cat0T = cat2 + 14680064;                          // 14,680,064
    bf16*  zrb   = cat0T + 14680064;                         // 25,165,824

    // ---- d_ws layout (~107 MB; ws >= 173 MB, r3) ----
    const size_t NEED = 106979328;
    if (ws_size < NEED){
        ws_probe_kernel<<<3072, 256, 0, stream>>>(out_output, (float)(ws_size >> 20));
        return;
    }
    float*  Sf    = (float*)d_ws;                // 1,048,576 f32
    float*  T2f   = Sf + 1048576;                // 1,048,576 f32
    ushort* Sh    = (ushort*)(T2f + 1048576);    // [Sh|T2h] stacked hi
    ushort* T2h   = Sh  + 1048576;
    ushort* Sl    = T2h + 1048576;               // [Sl|T2l] stacked lo
    ushort* T2l   = Sl  + 1048576;
    bf16*   Sb    = (bf16*)(T2l + 1048576);      // [Sb|T2b] stacked bf16
    bf16*   T2b   = Sb + 1048576;
    ushort* wgETh = (ushort*)(T2b + 1048576);    // 3*256*160 = 122,880
    ushort* wgETl = wgETh + 122880;
    ushort* wuETh = wgETl + 122880;              // 3*128*160 = 61,440
    ushort* wuETl = wuETh + 61440;
    bf16*   wgDT  = (bf16*)(wuETl + 61440);      // 3*384*224 = 258,048
    bf16*   wuDT  = wgDT + 258048;               // 3*256*224 = 172,032
    float*  henc  = (float*)(wuDT + 172032);     // 8,388,608 f32
    float*  hdec  = henc + 8388608;              // 12,582,912 f32
    float*  go    = hdec + 12582912;             // 65,536 f32
    int*    ind0  = (int*)(go + 65536);          // 65,536 int

    hipMemsetAsync(henc, 0, (size_t)8388608*4, stream);
    hipMemsetAsync(go,   0, (size_t)65536*4,   stream);

    supports_kernel<<<Nn, 256, 0, stream>>>(emb, Sf);
    t2_gemm<<<dim3(16,16), 256, 0, stream>>>(Sf, T2f);
    conv_split<<<4096, 256, 0, stream>>>(Sf,  Sh,  Sl,  4096.f);
    conv_split<<<4096, 256, 0, stream>>>(T2f, T2h, T2l, 4096.f);
    conv_f2b<<<4096, 256, 0, stream>>>(Sf,  Sb);
    conv_f2b<<<4096, 256, 0, stream>>>(T2f, T2b);
    conv_w_split_T<<<480, 256, 0, stream>>>(eWg, wgETh, wgETl, 129, CPe, 256);
    conv_w_split_T<<<240, 256, 0, stream>>>(eWu, wuETh, wuETl, 129, CPe, 128);
    conv_w_T<<<1008, 256, 0, stream>>>(dWg, wgDT, 194, CPd, 384, 384);
    conv_w_T<<<672,  256, 0, stream>>>(dWu, wuDT, 194, CPd, 192, 256);

    const size_t SL = (size_t)65536*CPe;         // 10,485,760 = 1024*JPe (contig!)

    // -------- encoder: 12 steps, split-fp16 MFMA; XCD-grouped GCN --------
    for (int t = 0; t < Tt; ++t){
        build_encT<1><<<dim3(JPe/64, 16), 256, 0, stream>>>(
            x, henc, nullptr, catEh, catEl, catETh, catETl, t);
        mfma_split<0><<<dim3((JPe/128)*16), 256, 0, stream>>>(
            Sh, Sl, nullptr, nullptr, nullptr, nullptr,
            catETh, catETl, nullptr, nullptr, nullptr, nullptr,
            1, Nn, Nn, Nn,
            catEh + SL, catEl + SL, JPe, JPe, nullptr, 0, nullptr, nullptr, nullptr, 0,
            JPe/128);
        mfma_split<1><<<dim3(2, 512), 256, 0, stream>>>(
            catEh, catEl, catEh + SL, catEl + SL, catEh + 2*SL, catEl + 2*SL,
            wgETh, wgETl, wgETh + 40960, wgETl + 40960, wgETh + 81920, wgETl + 81920,
            3, CPe, CPe, CPe,
            nullptr, nullptr, 0, 256, zrE, ZRE, ebg, nullptr, nullptr, 0, 0);
        build_encT<2><<<dim3(JPe/64, 16), 256, 0, stream>>>(
            x, henc, zrE, catEh, catEl, catETh, catETl, t);
        mfma_split<0><<<dim3((JPe/128)*16), 256, 0, stream>>>(
            Sh, Sl, nullptr, nullptr, nullptr, nullptr,
            catETh, catETl, nullptr, nullptr, nullptr, nullptr,
            1, Nn, Nn, Nn,
            catEh + SL, catEl + SL, JPe, JPe, nullptr, 0, nullptr, nullptr, nullptr, 0,
            JPe/128);
        mfma_split<2><<<dim3(1, 512), 256, 0, stream>>>(
            catEh, catEl, catEh + SL, catEl + SL, catEh + 2*SL, catEl + 2*SL,
            wuETh, wuETl, wuETh + 20480, wuETl + 20480, wuETh + 40960, wuETl + 40960,
            3, CPe, CPe, CPe,
            nullptr, nullptr, 0, 128, nullptr, ZRE, ebu, zrE, henc, 128, 0);
    }

    // -------- attention (fp32 scores -> exact argmax) --------
    attn_kernel<<<65536, 64, 0, stream>>>(henc, Wq, Mem, hdec, ind0,
                                          out_value, out_query, out_pos);

    const ushort* Su   = (const ushort*)Sb;      // stacked [Sb|T2b]
    const ushort* c0u  = (const ushort*)cat0;
    const ushort* c1u  = (const ushort*)cat1;
    const ushort* c2u  = (const ushort*)cat2;
    const ushort* c0Tu = (const ushort*)cat0T;

    // -------- decoder: 12 steps, bf16 MFMA; XCD-grouped GCN --------
    for (int t = 0; t < HORt; ++t){
        build_decT<1><<<dim3(JPd/64, 16), 256, 0, stream>>>(
            go, ycov, hdec, nullptr, cat0, cat0T, t);
        mfma_gemm<0><<<dim3((JPd/128)*16), 256, 0, stream>>>(
            Su, nullptr, nullptr, c0Tu, nullptr, nullptr, 1, 1024, 1024, 1024,
            cat1, JPd, JPd, nullptr, nullptr, nullptr, 0, JPd/128);
        mfma_gemm<1><<<dim3(3, 512), 256, 0, stream>>>(
            c0u, c1u, c2u,
            (const ushort*)wgDT, (const ushort*)(wgDT + 86016), (const ushort*)(wgDT + 172032),
            3, CPd, CPd, CPd, zrb, LDZR, 384, dbg, nullptr, nullptr, 0, 0);
        build_decT<2><<<dim3(JPd/64, 16), 256, 0, stream>>>(
            go, ycov, hdec, zrb, cat0, cat0T, t);
        mfma_gemm<0><<<dim3((JPd/128)*16), 256, 0, stream>>>(
            Su, nullptr, nullptr, c0Tu, nullptr, nullptr, 1, 1024, 1024, 1024,
            cat1, JPd, JPd, nullptr, nullptr, nullptr, 0, JPd/128);
        mfma_gemm<2><<<dim3(2, 512), 256, 0, stream>>>(
            c0u, c1u, c2u,
            (const ushort*)wuDT, (const ushort*)(wuDT + 57344), (const ushort*)(wuDT + 114688),
            3, CPd, CPd, CPd, nullptr, 0, 192, dbu, zrb, hdec, 192, 0);
        proj_kernel<<<16384, 256, 0, stream>>>(hdec, pW, pb, go, out_output, t);
    }

    // -------- aux outputs LAST --------
    neg_kernel<<<327680, 256, 0, stream>>>(Mem, out_neg);
    mask_kernel<<<5120, 256, 0, stream>>>(ind0, out_mask);
}